// Round 8
// baseline (305.332 us; speedup 1.0000x reference)
//
#include <hip/hip_runtime.h>
#include <stdint.h>

#define SEQ 256
#define BATCH 32
#define IN_DIM 1024
#define HID 64
#define NPAD 1280
#define ROWS (SEQ*BATCH)   // 8192

// workspace byte offsets (all 256B aligned)
#define XBF_OFF   0
#define WBF_OFF   16777216
#define BB_OFF    19398656
#define GATE_OFF  19403776
#define Y_OFF     19534848
#define DM8_OFF   61477888   // 8-chunk ΔM (37,748,736 B) -> needs ws >= 99,226,624
#define DM8_END   99226624
// 4-chunk fallback ΔM (18,874,368 B) overlays Xbf/Wbf (dead after gemm)

// LDS tile geometry for the chunk kernels:
// row = [k0(64) | ka(64) | kb(64) | v0(64) | va(64) | vb(64) | q(64) | gate(4)]
#define TROW 452
#define TILEF (8*TROW)   // 3616 floats per buffer; x2 buffers = 28,928 B LDS

typedef __attribute__((ext_vector_type(8))) short short8;
typedef __attribute__((ext_vector_type(4))) float floatx4;

static __device__ __forceinline__ short f2bf(float f) {
  union { float f; uint32_t u; } a; a.f = f;
  uint32_t r = (a.u + 0x7FFFu + ((a.u >> 16) & 1u)) >> 16;  // RNE
  return (short)r;
}

// ---------------- prep: fp32 -> bf16 for X, concat+convert weights, concat bias ----------------
__global__ void prep_kernel(const float* __restrict__ X,
                            const float* __restrict__ Wk, const float* __restrict__ bk,
                            const float* __restrict__ Wv, const float* __restrict__ bv,
                            const float* __restrict__ Wg, const float* __restrict__ bg,
                            const float* __restrict__ Wq, const float* __restrict__ bq,
                            short* __restrict__ Xbf, short* __restrict__ Wbf,
                            float* __restrict__ bb)
{
  int64_t idx = (int64_t)blockIdx.x * blockDim.x + threadIdx.x;
  int64_t stride = (int64_t)gridDim.x * blockDim.x;
  const int64_t NX4 = (int64_t)ROWS * IN_DIM / 4;
  for (int64_t i = idx; i < NX4; i += stride) {
    float4 x = ((const float4*)X)[i];
    short4 s4;
    s4.x = f2bf(x.x); s4.y = f2bf(x.y); s4.z = f2bf(x.z); s4.w = f2bf(x.w);
    ((short4*)Xbf)[i] = s4;
  }
  const int64_t NW4 = (int64_t)NPAD * IN_DIM / 4;
  for (int64_t i = idx; i < NW4; i += stride) {
    int64_t e = i * 4;
    int r = (int)(e >> 10);
    int k = (int)(e & 1023);
    float4 x;
    if (r < 576)       x = *(const float4*)(Wk + (int64_t)r*1024 + k);
    else if (r < 1152) x = *(const float4*)(Wv + (int64_t)(r-576)*1024 + k);
    else if (r < 1216) x = *(const float4*)(Wq + (int64_t)(r-1152)*1024 + k);
    else               x = make_float4(0.f, 0.f, 0.f, 0.f);   // gate cols unused (fp32 gate kernel)
    short4 s4;
    s4.x = f2bf(x.x); s4.y = f2bf(x.y); s4.z = f2bf(x.z); s4.w = f2bf(x.w);
    ((short4*)Wbf)[i] = s4;
  }
  for (int64_t i = idx; i < NPAD; i += stride) {
    int r = (int)i; float v;
    if (r < 576)       v = bk[r];
    else if (r < 1152) v = bv[r - 576];
    else if (r < 1216) v = bq[r - 1152];
    else               v = 0.f;
    bb[r] = v;
  }
}

// ---------------- GEMM: Y[8192,1280] = Xbf @ Wbf^T + bb (bf16 MFMA, fp32 accum) ----------------
__global__ __launch_bounds__(256) void gemm_kernel(
    const short* __restrict__ Xbf,
    const short* __restrict__ Wbf,
    const float* __restrict__ bb,
    float* __restrict__ Y)
{
  __shared__ short8 AsV[256];  // 64 rows x 32 k, bf16
  __shared__ short8 BsV[256];
  short* As = (short*)AsV;
  short* Bs = (short*)BsV;

  const int tid  = threadIdx.x;
  const int lane = tid & 63;
  const int wv   = tid >> 6;     // 0..3
  const int quad = lane >> 4;    // 0..3
  const int cl   = lane & 15;
  const int m0 = blockIdx.y * 64;
  const int n0 = blockIdx.x * 64;

  const int srow = tid >> 2;         // 0..63
  const int scol = (tid & 3) * 8;    // 0,8,16,24
  const short* gA = Xbf + (int64_t)(m0 + srow) * IN_DIM + scol;
  const short* gB = Wbf + (int64_t)(n0 + srow) * IN_DIM + scol;
  short8* lA = (short8*)&As[srow * 32 + scol];
  short8* lB = (short8*)&Bs[srow * 32 + scol];

  floatx4 acc[4];
#pragma unroll
  for (int i = 0; i < 4; i++) acc[i] = (floatx4){0.f, 0.f, 0.f, 0.f};

  for (int ks = 0; ks < IN_DIM; ks += 32) {
    short8 ra = *(const short8*)(gA + ks);
    short8 rb = *(const short8*)(gB + ks);
    *lA = ra;
    *lB = rb;
    __syncthreads();
    short8 bfrag = *(const short8*)(&Bs[(wv * 16 + cl) * 32 + quad * 8]);
#pragma unroll
    for (int mt = 0; mt < 4; mt++) {
      short8 afrag = *(const short8*)(&As[(mt * 16 + cl) * 32 + quad * 8]);
      acc[mt] = __builtin_amdgcn_mfma_f32_16x16x32_bf16(afrag, bfrag, acc[mt], 0, 0, 0);
    }
    __syncthreads();
  }

  const int col = n0 + wv * 16 + cl;
  const float bias = bb[col];
#pragma unroll
  for (int mt = 0; mt < 4; mt++) {
#pragma unroll
    for (int r = 0; r < 4; r++) {
      int row = m0 + mt * 16 + quad * 4 + r;
      Y[(int64_t)row * NPAD + col] = acc[mt][r] + bias;
    }
  }
}

// ---------------- gate (fp32-exact): logits from X,Wg; top-2 + renormalized weights ----------------
__global__ __launch_bounds__(256) void gate_kernel(
    const float* __restrict__ X,
    const float* __restrict__ Wg, const float* __restrict__ bg,
    float4* __restrict__ gate)
{
  const int lane = threadIdx.x & 63;
  const int row  = blockIdx.x * 4 + (threadIdx.x >> 6);
  const float* x = X + (int64_t)row * IN_DIM;

  float acc[8];
#pragma unroll
  for (int e = 0; e < 8; e++) acc[e] = 0.f;

#pragma unroll
  for (int i = 0; i < 4; i++) {
    const int off = i * 256 + lane * 4;
    float4 xv = *(const float4*)(x + off);
#pragma unroll
    for (int e = 0; e < 8; e++) {
      float4 wv = *(const float4*)(Wg + e * IN_DIM + off);
      acc[e] += xv.x * wv.x + xv.y * wv.y + xv.z * wv.z + xv.w * wv.w;
    }
  }
#pragma unroll
  for (int e = 0; e < 8; e++) {
#pragma unroll
    for (int m = 32; m >= 1; m >>= 1)
      acc[e] += __shfl_xor(acc[e], m);
    acc[e] += bg[e];
  }

  if (lane == 0) {
    int i0 = 0; float v0 = acc[0];
#pragma unroll
    for (int e = 1; e < 8; e++) if (acc[e] > v0) { v0 = acc[e]; i0 = e; }
    int i1 = -1; float v1 = -3.4e38f;
#pragma unroll
    for (int e = 0; e < 8; e++) if (e != i0 && acc[e] > v1) { v1 = acc[e]; i1 = e; }
    float e1 = __expf(v1 - v0);
    float inv = 1.f / (1.f + e1);
    gate[row] = make_float4(__int_as_float(i0), __int_as_float(i1), inv, e1 * inv);
  }
}

// 16-lane (DPP row) sum; result valid in lane (lane&15)==15 of each row.
static __device__ __forceinline__ float row16_sum(float x) {
  float r = x;
  r += __int_as_float(__builtin_amdgcn_update_dpp(0, __float_as_int(r), 0x118, 0xf, 0xf, false)); // row_shr:8
  r += __int_as_float(__builtin_amdgcn_update_dpp(0, __float_as_int(r), 0x114, 0xf, 0xf, false)); // row_shr:4
  r += __int_as_float(__builtin_amdgcn_update_dpp(0, __float_as_int(r), 0x112, 0xf, 0xf, false)); // row_shr:2
  r += __int_as_float(__builtin_amdgcn_update_dpp(0, __float_as_int(r), 0x111, 0xf, 0xf, false)); // row_shr:1
  return r;
}

// ======================= chunked scan with LDS tile staging =======================
// R7 post-mortem: per-step chain was still ~1765 cyc of exposed global latency;
// total ≈ 65536·lat/resident_blocks regardless of chunk count. Fix = kill lat:
// stage gate-routed Y columns into LDS tiles (8 rows, fixed segment offsets), so
// the compute-side LDS addresses are STATIC; the only per-step dependency is the
// ~60-cyc M-update VALU chain. Double-buffered tiles; global loads issued AFTER
// the barrier (compiler drains vmcnt before s_barrier) so their wait lands at
// the ds_write, a full compute-phase later. 256-thr blocks / 16 j -> 1024 blocks
// = 4 blocks/CU (one residency batch), 28,928 B LDS (5 blocks/CU allowed).

// staging: thread (srow_=tid>>5, rtid_=tid&31) stages row srow_ of the tile:
// 112 float4 of segment data + the row's gate.
#define STAGE_REGS(TBASE) {                                          \
    const int trow = (TBASE) + srow_;                                \
    gs = gate[trow * BATCH + b];                                     \
    const int si0 = __float_as_int(gs.x);                            \
    const int si1 = __float_as_int(gs.y);                            \
    const float* Yp = Y + ((int64_t)trow * BATCH + b) * NPAD;        \
    _Pragma("unroll")                                                \
    for (int k = 0; k < 4; k++) {                                    \
      const int idx = rtid_ + 32 * k;                                \
      if (idx < 112) {                                               \
        const int seg = idx >> 4;                                    \
        const int off = (idx & 15) * 4;                              \
        const int base = (seg == 6) ? 1152 : ((seg >= 3) ? 576 : 0); \
        const int s3 = (seg >= 3 && seg < 6) ? seg - 3 : seg;        \
        const int slot = (s3 == 1) ? si0 * 64 : ((s3 == 2) ? si1 * 64 : 0); \
        sd[k] = *(const float4*)(Yp + base + slot + off);            \
      }                                                              \
    } }

#define STAGE_WRITE(DST) {                                           \
    float* dbuf = sY + (DST) * TILEF + srow_ * TROW;                 \
    _Pragma("unroll")                                                \
    for (int k = 0; k < 4; k++) {                                    \
      const int idx = rtid_ + 32 * k;                                \
      if (idx < 112) *(float4*)(dbuf + idx * 4) = sd[k];             \
    }                                                                \
    if (rtid_ == 0) *(float4*)(dbuf + 448) = gs; }

// ---------------- phase A: per-chunk delta accumulation ----------------
__global__ __launch_bounds__(256) void chunk_accum_kernel(
    const float* __restrict__ Y, const float4* __restrict__ gate,
    float* __restrict__ DM, int ncMask, int ncShift, int L)
{
  __shared__ float sY[2 * TILEF];
  const int blk  = blockIdx.x;
  const int c    = blk & ncMask;
  const int rest = blk >> ncShift;
  const int jblk = rest & 3;
  const int b    = rest >> 2;
  const int tid  = threadIdx.x;
  const int lane = tid & 63;
  const int wv   = tid >> 6;        // 0..3
  const int igrp = lane & 15;
  const int jloc = lane >> 4;
  const int j    = jblk * 16 + wv * 4 + jloc;
  const int ib   = igrp * 4;
  const int srow_ = tid >> 5;       // 0..7 (staging row)
  const int rtid_ = tid & 31;
  const int t0   = c * L;
  const int NT   = L / 8;

  float D[9][4];
#pragma unroll
  for (int m = 0; m < 9; m++)
#pragma unroll
    for (int ii = 0; ii < 4; ii++) D[m][ii] = 0.f;

  float4 sd[4]; float4 gs;

#define ACC(mm, KK, VV) {                                   \
    D[mm][0] += KK.x * VV; D[mm][1] += KK.y * VV;           \
    D[mm][2] += KK.z * VV; D[mm][3] += KK.w * VV; }

#define CSTEP_A(P, R) {                                     \
    const float* rb = sY + (P) * TILEF + (R) * TROW;        \
    float4 gl = *(const float4*)(rb + 448);                 \
    float4 k0 = *(const float4*)(rb + ib);                  \
    float4 ka = *(const float4*)(rb + 64 + ib);             \
    float4 kb = *(const float4*)(rb + 128 + ib);            \
    float v0 = rb[192 + j];                                 \
    float va = rb[256 + j];                                 \
    float vb = rb[320 + j];                                 \
    const int i0 = __float_as_int(gl.x);                    \
    const int i1 = __float_as_int(gl.y);                    \
    ACC(0, k0, v0);                                         \
    switch (i0) {                                           \
      case 0: ACC(0, ka, va); break;                        \
      case 1: ACC(1, ka, va); break;                        \
      case 2: ACC(2, ka, va); break;                        \
      case 3: ACC(3, ka, va); break;                        \
      case 4: ACC(4, ka, va); break;                        \
      case 5: ACC(5, ka, va); break;                        \
      case 6: ACC(6, ka, va); break;                        \
      default: ACC(7, ka, va); break;                       \
    }                                                       \
    switch (i1) {                                           \
      case 0: ACC(0, kb, vb); break;                        \
      case 1: ACC(1, kb, vb); break;                        \
      case 2: ACC(2, kb, vb); break;                        \
      case 3: ACC(3, kb, vb); break;                        \
      case 4: ACC(4, kb, vb); break;                        \
      case 5: ACC(5, kb, vb); break;                        \
      case 6: ACC(6, kb, vb); break;                        \
      default: ACC(7, kb, vb); break;                       \
    } }

  STAGE_REGS(t0);
  STAGE_WRITE(0);

  for (int tile = 0; tile < NT; ++tile) {
    const int p = tile & 1;
    __syncthreads();
    if (tile + 1 < NT) STAGE_REGS(t0 + (tile + 1) * 8);
#pragma unroll
    for (int r = 0; r < 8; r++) CSTEP_A(p, r);
    if (tile + 1 < NT) STAGE_WRITE(p ^ 1);
  }
#undef CSTEP_A
#undef ACC

  float* dmb = DM + ((int64_t)(c * 32 + b)) * 36864;
#pragma unroll
  for (int m = 0; m < 9; m++)
#pragma unroll
    for (int ii = 0; ii < 4; ii++)
      dmb[m * 4096 + (ib + ii) * 64 + j] = D[m][ii];
}

// ---------------- phase B: in-place exclusive prefix (+M0) over chunks ----------------
__global__ void prefix_kernel(const float* __restrict__ M0, float* __restrict__ DM, int nc)
{
  int64_t e = (int64_t)blockIdx.x * blockDim.x + threadIdx.x;   // < 32*36864
  int b = (int)(e / 36864);
  int r = (int)(e % 36864);
  float run = M0[e];
  for (int cc = 0; cc < nc; cc++) {
    int64_t idx = ((int64_t)(cc * 32 + b)) * 36864 + r;
    float tmp = DM[idx];
    DM[idx] = run;
    run += tmp;
  }
}

// ---------------- phase C: intra-chunk recurrence + readout ----------------
__global__ __launch_bounds__(256) void chunk_scan_kernel(
    const float* __restrict__ Y, const float4* __restrict__ gate,
    const float* __restrict__ DM,   // holds Mstart(c) after prefix
    float* __restrict__ out, int ncMask, int ncShift, int L)
{
  __shared__ float sY[2 * TILEF];
  const int blk  = blockIdx.x;
  const int c    = blk & ncMask;
  const int rest = blk >> ncShift;
  const int jblk = rest & 3;
  const int b    = rest >> 2;
  const int tid  = threadIdx.x;
  const int lane = tid & 63;
  const int wv   = tid >> 6;        // 0..3
  const int igrp = lane & 15;
  const int jloc = lane >> 4;
  const int j    = jblk * 16 + wv * 4 + jloc;
  const int ib   = igrp * 4;
  const int srow_ = tid >> 5;
  const int rtid_ = tid & 31;
  const int t0   = c * L;
  const int NT   = L / 8;

  float M[9][4];
  const float* msb = DM + ((int64_t)(c * 32 + b)) * 36864;
#pragma unroll
  for (int m = 0; m < 9; m++)
#pragma unroll
    for (int ii = 0; ii < 4; ii++)
      M[m][ii] = msb[m * 4096 + (ib + ii) * 64 + j];

  float4 sd[4]; float4 gs;

#define DO_SLOT(mm, gw, KK, VV) {                                            \
      M[mm][0] += KK.x * VV; M[mm][1] += KK.y * VV;                          \
      M[mm][2] += KK.z * VV; M[mm][3] += KK.w * VV;                          \
      Mc0 += (gw) * M[mm][0]; Mc1 += (gw) * M[mm][1];                        \
      Mc2 += (gw) * M[mm][2]; Mc3 += (gw) * M[mm][3]; }

    // routed slot == 0: add the delta unweighted too (all scatter-adds precede readout)
#define DO_SLOT0(gw, KK, VV) {                                               \
      float d0 = KK.x * VV, d1 = KK.y * VV, d2 = KK.z * VV, d3 = KK.w * VV;  \
      M[0][0] += d0; M[0][1] += d1; M[0][2] += d2; M[0][3] += d3;            \
      Mc0 += d0 + (gw) * M[0][0]; Mc1 += d1 + (gw) * M[0][1];                \
      Mc2 += d2 + (gw) * M[0][2]; Mc3 += d3 + (gw) * M[0][3]; }

#define CSTEP_C(P, R, TT) {                                                  \
    const float* rb = sY + (P) * TILEF + (R) * TROW;                         \
    float4 gl = *(const float4*)(rb + 448);                                  \
    float4 k0 = *(const float4*)(rb + ib);                                   \
    float4 ka = *(const float4*)(rb + 64 + ib);                              \
    float4 kb = *(const float4*)(rb + 128 + ib);                             \
    float v0 = rb[192 + j];                                                  \
    float va = rb[256 + j];                                                  \
    float vb = rb[320 + j];                                                  \
    float4 qv = *(const float4*)(rb + 384 + ib);                             \
    const int i0 = __float_as_int(gl.x);                                     \
    const int i1 = __float_as_int(gl.y);                                     \
    const float g0w = gl.z, g1w = gl.w;                                      \
    float Mc0, Mc1, Mc2, Mc3;                                                \
    M[0][0] += k0.x * v0; M[0][1] += k0.y * v0;                              \
    M[0][2] += k0.z * v0; M[0][3] += k0.w * v0;                              \
    Mc0 = M[0][0]; Mc1 = M[0][1]; Mc2 = M[0][2]; Mc3 = M[0][3];              \
    switch (i0) {                                                            \
      case 0: DO_SLOT0(g0w, ka, va); break;                                  \
      case 1: DO_SLOT(1, g0w, ka, va); break;                                \
      case 2: DO_SLOT(2, g0w, ka, va); break;                                \
      case 3: DO_SLOT(3, g0w, ka, va); break;                                \
      case 4: DO_SLOT(4, g0w, ka, va); break;                                \
      case 5: DO_SLOT(5, g0w, ka, va); break;                                \
      case 6: DO_SLOT(6, g0w, ka, va); break;                                \
      default: DO_SLOT(7, g0w, ka, va); break;                               \
    }                                                                        \
    switch (i1) {                                                            \
      case 0: DO_SLOT0(g1w, kb, vb); break;                                  \
      case 1: DO_SLOT(1, g1w, kb, vb); break;                                \
      case 2: DO_SLOT(2, g1w, kb, vb); break;                                \
      case 3: DO_SLOT(3, g1w, kb, vb); break;                                \
      case 4: DO_SLOT(4, g1w, kb, vb); break;                                \
      case 5: DO_SLOT(5, g1w, kb, vb); break;                                \
      case 6: DO_SLOT(6, g1w, kb, vb); break;                                \
      default: DO_SLOT(7, g1w, kb, vb); break;                               \
    }                                                                        \
    float part = qv.x * Mc0 + qv.y * Mc1 + qv.z * Mc2 + qv.w * Mc3;          \
    part = row16_sum(part);                                                  \
    if (igrp == 15)                                                          \
      out[(int64_t)(TT) * (BATCH * HID) + b * HID + j] = part; }

  STAGE_REGS(t0);
  STAGE_WRITE(0);

  for (int tile = 0; tile < NT; ++tile) {
    const int p = tile & 1;
    __syncthreads();
    if (tile + 1 < NT) STAGE_REGS(t0 + (tile + 1) * 8);
#pragma unroll
    for (int r = 0; r < 8; r++) CSTEP_C(p, r, t0 + tile * 8 + r);
    if (tile + 1 < NT) STAGE_WRITE(p ^ 1);
  }
#undef CSTEP_C
#undef DO_SLOT
#undef DO_SLOT0

  if (c == ncMask) {   // last chunk owns M_final
    float* Mf = out + (int64_t)SEQ * BATCH * HID + (int64_t)b * 36864;
#pragma unroll
    for (int m = 0; m < 9; m++)
#pragma unroll
      for (int ii = 0; ii < 4; ii++)
        Mf[m * 4096 + (ib + ii) * 64 + j] = M[m][ii];
  }
}

// ---------------- launch ----------------
extern "C" void kernel_launch(void* const* d_in, const int* in_sizes, int n_in,
                              void* d_out, int out_size, void* d_ws, size_t ws_size,
                              hipStream_t stream)
{
  const float* X  = (const float*)d_in[0];
  const float* M0 = (const float*)d_in[1];
  const float* Wk = (const float*)d_in[2];
  const float* bk = (const float*)d_in[3];
  const float* Wv = (const float*)d_in[4];
  const float* bv = (const float*)d_in[5];
  const float* Wg = (const float*)d_in[6];
  const float* bg = (const float*)d_in[7];
  const float* Wq = (const float*)d_in[8];
  const float* bq = (const float*)d_in[9];

  char* ws = (char*)d_ws;
  short*  Xbf  = (short*)(ws + XBF_OFF);
  short*  Wbf  = (short*)(ws + WBF_OFF);
  float*  bb   = (float*)(ws + BB_OFF);
  float4* gate = (float4*)(ws + GATE_OFF);
  float*  Y    = (float*)(ws + Y_OFF);
  float*  out  = (float*)d_out;

  // chunk count: 8 if ws has room for a fresh ΔM region; else 4 chunks reusing
  // the Xbf/Wbf region (dead after gemm). ws_size is constant per deployment,
  // so this branch is deterministic across calls (graph-safe).
  int nc, ncShift; size_t dm_off;
  if (ws_size >= (size_t)DM8_END) { nc = 8; ncShift = 3; dm_off = DM8_OFF; }
  else                            { nc = 4; ncShift = 2; dm_off = 0; }
  const int L = SEQ / nc;
  float* DM = (float*)(ws + dm_off);

  prep_kernel<<<2048, 256, 0, stream>>>(X, Wk, bk, Wv, bv, Wg, bg, Wq, bq, Xbf, Wbf, bb);
  gate_kernel<<<ROWS / 4, 256, 0, stream>>>(X, Wg, bg, gate);
  dim3 gg(NPAD / 64, ROWS / 64);
  gemm_kernel<<<gg, 256, 0, stream>>>(Xbf, Wbf, bb, Y);
  chunk_accum_kernel<<<32 * nc * 4, 256, 0, stream>>>(Y, gate, DM, nc - 1, ncShift, L);
  prefix_kernel<<<(32 * 36864) / 256, 256, 0, stream>>>(M0, DM, nc);
  chunk_scan_kernel<<<32 * nc * 4, 256, 0, stream>>>(Y, gate, DM, out, nc - 1, ncShift, L);
}

// Round 9
// 268.095 us; speedup vs baseline: 1.1389x; 1.1389x over previous
//
#include <hip/hip_runtime.h>
#include <stdint.h>

#define SEQ 256
#define BATCH 32
#define IN_DIM 1024
#define HID 64
#define NPAD 1280
#define ROWS (SEQ*BATCH)   // 8192

// workspace byte offsets (all 256B aligned)
#define XBF_OFF   0
#define WBF_OFF   16777216
#define BB_OFF    19398656
#define GATE_OFF  19403776
#define Y_OFF     19534848
#define DM8_OFF   61477888   // 8-chunk ΔM (37,748,736 B) -> needs ws >= 99,226,624
#define DM8_END   99226624
// 4-chunk fallback ΔM (18,874,368 B) overlays Xbf/Wbf (dead after gemm)

// LDS tile geometry for the chunk kernels:
// row = [k0(64) | ka(64) | kb(64) | v0(64) | va(64) | vb(64) | q(64) | gate(4)]
#define TROW 452
#define TILEF (8*TROW)   // 3616 floats per buffer; x2 buffers = 28,928 B LDS

typedef __attribute__((ext_vector_type(8))) short short8;
typedef __attribute__((ext_vector_type(4))) float floatx4;

// async global->LDS DMA, 16B per lane, dest = wave-uniform base + lane*16
// (builtin sig: void(v*1, v*3, Ui size, i offset, Ui aux) — verified gfx950, m97)
typedef const __attribute__((address_space(1))) unsigned int gas_u32;
typedef __attribute__((address_space(3))) unsigned int las_u32;
static __device__ __forceinline__ void gl_lds16(const void* g, void* l) {
  __builtin_amdgcn_global_load_lds((gas_u32*)g, (las_u32*)l, 16, 0, 0);
}

static __device__ __forceinline__ short f2bf(float f) {
  union { float f; uint32_t u; } a; a.f = f;
  uint32_t r = (a.u + 0x7FFFu + ((a.u >> 16) & 1u)) >> 16;  // RNE
  return (short)r;
}

// ---------------- prep: fp32 -> bf16 for X, concat+convert weights, concat bias ----------------
__global__ void prep_kernel(const float* __restrict__ X,
                            const float* __restrict__ Wk, const float* __restrict__ bk,
                            const float* __restrict__ Wv, const float* __restrict__ bv,
                            const float* __restrict__ Wg, const float* __restrict__ bg,
                            const float* __restrict__ Wq, const float* __restrict__ bq,
                            short* __restrict__ Xbf, short* __restrict__ Wbf,
                            float* __restrict__ bb)
{
  int64_t idx = (int64_t)blockIdx.x * blockDim.x + threadIdx.x;
  int64_t stride = (int64_t)gridDim.x * blockDim.x;
  const int64_t NX4 = (int64_t)ROWS * IN_DIM / 4;
  for (int64_t i = idx; i < NX4; i += stride) {
    float4 x = ((const float4*)X)[i];
    short4 s4;
    s4.x = f2bf(x.x); s4.y = f2bf(x.y); s4.z = f2bf(x.z); s4.w = f2bf(x.w);
    ((short4*)Xbf)[i] = s4;
  }
  const int64_t NW4 = (int64_t)NPAD * IN_DIM / 4;
  for (int64_t i = idx; i < NW4; i += stride) {
    int64_t e = i * 4;
    int r = (int)(e >> 10);
    int k = (int)(e & 1023);
    float4 x;
    if (r < 576)       x = *(const float4*)(Wk + (int64_t)r*1024 + k);
    else if (r < 1152) x = *(const float4*)(Wv + (int64_t)(r-576)*1024 + k);
    else if (r < 1216) x = *(const float4*)(Wq + (int64_t)(r-1152)*1024 + k);
    else               x = make_float4(0.f, 0.f, 0.f, 0.f);   // gate cols unused (fp32 gate kernel)
    short4 s4;
    s4.x = f2bf(x.x); s4.y = f2bf(x.y); s4.z = f2bf(x.z); s4.w = f2bf(x.w);
    ((short4*)Wbf)[i] = s4;
  }
  for (int64_t i = idx; i < NPAD; i += stride) {
    int r = (int)i; float v;
    if (r < 576)       v = bk[r];
    else if (r < 1152) v = bv[r - 576];
    else if (r < 1216) v = bq[r - 1152];
    else               v = 0.f;
    bb[r] = v;
  }
}

// ---------------- GEMM: Y[8192,1280] = Xbf @ Wbf^T + bb ----------------
// m97-style: 128x128 tile, BK=32, 256 thr, 2x2 wave grid, 4x4 MFMAs/wave,
// global_load_lds width-16 staging. Lane->LDS map: lane l lands at base+l*16B
// = row (l>>2), col (l&3)*8 of a 64B-row tile chunk (verified arithmetic).
__global__ __launch_bounds__(256) void gemm_kernel(
    const short* __restrict__ Xbf,
    const short* __restrict__ Wbf,
    const float* __restrict__ bb,
    float* __restrict__ Y)
{
  __shared__ short As[128 * 32];   // 8 KB
  __shared__ short Bs[128 * 32];   // 8 KB

  const int tid  = threadIdx.x;
  const int lane = tid & 63;
  const int wv   = tid >> 6;     // 0..3
  const int quad = lane >> 4;    // 0..3
  const int cl   = lane & 15;
  const int wm   = wv & 1;       // wave M-half
  const int wn   = wv >> 1;      // wave N-half
  const int m0 = blockIdx.y * 128;
  const int n0 = blockIdx.x * 128;

  // staging: wave wv stages rows [wv*32, wv*32+32) of A and B, 2 DMA insts each
  const int srow = wv * 32 + (lane >> 2);
  const int scol = (lane & 3) * 8;
  const short* gA = Xbf + (int64_t)(m0 + srow) * IN_DIM + scol;
  const short* gB = Wbf + (int64_t)(n0 + srow) * IN_DIM + scol;
  short* lA = As + (wv * 32) * 32;   // wave-uniform LDS base
  short* lB = Bs + (wv * 32) * 32;

  floatx4 acc[4][4];
#pragma unroll
  for (int i = 0; i < 4; i++)
#pragma unroll
    for (int k = 0; k < 4; k++) acc[i][k] = (floatx4){0.f, 0.f, 0.f, 0.f};

  for (int ks = 0; ks < IN_DIM; ks += 32) {
    gl_lds16(gA + ks,                lA);
    gl_lds16(gA + 16 * IN_DIM + ks,  lA + 16 * 32);
    gl_lds16(gB + ks,                lB);
    gl_lds16(gB + 16 * IN_DIM + ks,  lB + 16 * 32);
    __syncthreads();   // drains vmcnt (DMA) before barrier

    short8 bfrag[4], afrag[4];
#pragma unroll
    for (int nt = 0; nt < 4; nt++)
      bfrag[nt] = *(const short8*)(&Bs[(wn * 64 + nt * 16 + cl) * 32 + quad * 8]);
#pragma unroll
    for (int mt = 0; mt < 4; mt++)
      afrag[mt] = *(const short8*)(&As[(wm * 64 + mt * 16 + cl) * 32 + quad * 8]);
#pragma unroll
    for (int mt = 0; mt < 4; mt++)
#pragma unroll
      for (int nt = 0; nt < 4; nt++)
        acc[mt][nt] = __builtin_amdgcn_mfma_f32_16x16x32_bf16(afrag[mt], bfrag[nt], acc[mt][nt], 0, 0, 0);
    __syncthreads();
  }

#pragma unroll
  for (int nt = 0; nt < 4; nt++) {
    const int col = n0 + wn * 64 + nt * 16 + cl;
    const float bias = bb[col];
#pragma unroll
    for (int mt = 0; mt < 4; mt++) {
#pragma unroll
      for (int r = 0; r < 4; r++) {
        int row = m0 + wm * 64 + mt * 16 + quad * 4 + r;
        Y[(int64_t)row * NPAD + col] = acc[mt][nt][r] + bias;
      }
    }
  }
}

// ---------------- gate (fp32-exact): logits from X,Wg; top-2 + renormalized weights ----------------
__global__ __launch_bounds__(256) void gate_kernel(
    const float* __restrict__ X,
    const float* __restrict__ Wg, const float* __restrict__ bg,
    float4* __restrict__ gate)
{
  const int lane = threadIdx.x & 63;
  const int row  = blockIdx.x * 4 + (threadIdx.x >> 6);
  const float* x = X + (int64_t)row * IN_DIM;

  float acc[8];
#pragma unroll
  for (int e = 0; e < 8; e++) acc[e] = 0.f;

#pragma unroll
  for (int i = 0; i < 4; i++) {
    const int off = i * 256 + lane * 4;
    float4 xv = *(const float4*)(x + off);
#pragma unroll
    for (int e = 0; e < 8; e++) {
      float4 wv = *(const float4*)(Wg + e * IN_DIM + off);
      acc[e] += xv.x * wv.x + xv.y * wv.y + xv.z * wv.z + xv.w * wv.w;
    }
  }
#pragma unroll
  for (int e = 0; e < 8; e++) {
#pragma unroll
    for (int m = 32; m >= 1; m >>= 1)
      acc[e] += __shfl_xor(acc[e], m);
    acc[e] += bg[e];
  }

  if (lane == 0) {
    int i0 = 0; float v0 = acc[0];
#pragma unroll
    for (int e = 1; e < 8; e++) if (acc[e] > v0) { v0 = acc[e]; i0 = e; }
    int i1 = -1; float v1 = -3.4e38f;
#pragma unroll
    for (int e = 0; e < 8; e++) if (e != i0 && acc[e] > v1) { v1 = acc[e]; i1 = e; }
    float e1 = __expf(v1 - v0);
    float inv = 1.f / (1.f + e1);
    gate[row] = make_float4(__int_as_float(i0), __int_as_float(i1), inv, e1 * inv);
  }
}

// 16-lane (DPP row) sum; result valid in lane (lane&15)==15 of each row.
static __device__ __forceinline__ float row16_sum(float x) {
  float r = x;
  r += __int_as_float(__builtin_amdgcn_update_dpp(0, __float_as_int(r), 0x118, 0xf, 0xf, false)); // row_shr:8
  r += __int_as_float(__builtin_amdgcn_update_dpp(0, __float_as_int(r), 0x114, 0xf, 0xf, false)); // row_shr:4
  r += __int_as_float(__builtin_amdgcn_update_dpp(0, __float_as_int(r), 0x112, 0xf, 0xf, false)); // row_shr:2
  r += __int_as_float(__builtin_amdgcn_update_dpp(0, __float_as_int(r), 0x111, 0xf, 0xf, false)); // row_shr:1
  return r;
}

// ======================= chunked scan with LDS tile staging =======================
// R8 post-mortem: STAGE_REGS held sd[4]+gs live across the 8-step compute ->
// compiler (80-VGPR budget) spilled to scratch (WRITE_SIZE 36MB vs 7.8MB real).
// R9: order per tile = sync -> compute(p) -> stage(p^1) with stage as
// load->immediate ds_write (short live ranges, no spill; ds_reads precede the
// writes so no false serialization). Per-wave stage latency is exposed but
// hidden by the other waves' compute (4 waves/SIMD). Race-safe: stage writes
// p^1 after sync(t), all waves done reading p^1 (previous iteration).

#define STAGE_TILE(TBASE, DST) {                                     \
    const int trow = (TBASE) + srow_;                                \
    float4 gs = gate[trow * BATCH + b];                              \
    const int si0 = __float_as_int(gs.x);                            \
    const int si1 = __float_as_int(gs.y);                            \
    const float* Yp = Y + ((int64_t)trow * BATCH + b) * NPAD;        \
    float* dbuf = sY + (DST) * TILEF + srow_ * TROW;                 \
    _Pragma("unroll")                                                \
    for (int k = 0; k < 4; k++) {                                    \
      const int idx = rtid_ + 32 * k;                                \
      if (idx < 112) {                                               \
        const int seg = idx >> 4;                                    \
        const int off = (idx & 15) * 4;                              \
        const int base = (seg == 6) ? 1152 : ((seg >= 3) ? 576 : 0); \
        const int s3 = (seg >= 3 && seg < 6) ? seg - 3 : seg;        \
        const int slot = (s3 == 1) ? si0 * 64 : ((s3 == 2) ? si1 * 64 : 0); \
        *(float4*)(dbuf + idx * 4) = *(const float4*)(Yp + base + slot + off); \
      }                                                              \
    }                                                                \
    if (rtid_ == 0) *(float4*)(dbuf + 448) = gs; }

// ---------------- phase A: per-chunk delta accumulation ----------------
__global__ __launch_bounds__(256) void chunk_accum_kernel(
    const float* __restrict__ Y, const float4* __restrict__ gate,
    float* __restrict__ DM, int ncMask, int ncShift, int L)
{
  __shared__ float sY[2 * TILEF];
  const int blk  = blockIdx.x;
  const int c    = blk & ncMask;
  const int rest = blk >> ncShift;
  const int jblk = rest & 3;
  const int b    = rest >> 2;
  const int tid  = threadIdx.x;
  const int lane = tid & 63;
  const int wv   = tid >> 6;        // 0..3
  const int igrp = lane & 15;
  const int jloc = lane >> 4;
  const int j    = jblk * 16 + wv * 4 + jloc;
  const int ib   = igrp * 4;
  const int srow_ = tid >> 5;       // 0..7 (staging row)
  const int rtid_ = tid & 31;
  const int t0   = c * L;
  const int NT   = L / 8;

  float D[9][4];
#pragma unroll
  for (int m = 0; m < 9; m++)
#pragma unroll
    for (int ii = 0; ii < 4; ii++) D[m][ii] = 0.f;

#define ACC(mm, KK, VV) {                                   \
    D[mm][0] += KK.x * VV; D[mm][1] += KK.y * VV;           \
    D[mm][2] += KK.z * VV; D[mm][3] += KK.w * VV; }

#define CSTEP_A(P, R) {                                     \
    const float* rb = sY + (P) * TILEF + (R) * TROW;        \
    float4 gl = *(const float4*)(rb + 448);                 \
    float4 k0 = *(const float4*)(rb + ib);                  \
    float4 ka = *(const float4*)(rb + 64 + ib);             \
    float4 kb = *(const float4*)(rb + 128 + ib);            \
    float v0 = rb[192 + j];                                 \
    float va = rb[256 + j];                                 \
    float vb = rb[320 + j];                                 \
    const int i0 = __float_as_int(gl.x);                    \
    const int i1 = __float_as_int(gl.y);                    \
    ACC(0, k0, v0);                                         \
    switch (i0) {                                           \
      case 0: ACC(0, ka, va); break;                        \
      case 1: ACC(1, ka, va); break;                        \
      case 2: ACC(2, ka, va); break;                        \
      case 3: ACC(3, ka, va); break;                        \
      case 4: ACC(4, ka, va); break;                        \
      case 5: ACC(5, ka, va); break;                        \
      case 6: ACC(6, ka, va); break;                        \
      default: ACC(7, ka, va); break;                       \
    }                                                       \
    switch (i1) {                                           \
      case 0: ACC(0, kb, vb); break;                        \
      case 1: ACC(1, kb, vb); break;                        \
      case 2: ACC(2, kb, vb); break;                        \
      case 3: ACC(3, kb, vb); break;                        \
      case 4: ACC(4, kb, vb); break;                        \
      case 5: ACC(5, kb, vb); break;                        \
      case 6: ACC(6, kb, vb); break;                        \
      default: ACC(7, kb, vb); break;                       \
    } }

  STAGE_TILE(t0, 0);

  for (int tile = 0; tile < NT; ++tile) {
    const int p = tile & 1;
    __syncthreads();
#pragma unroll
    for (int r = 0; r < 8; r++) CSTEP_A(p, r);
    if (tile + 1 < NT) STAGE_TILE(t0 + (tile + 1) * 8, p ^ 1);
  }
#undef CSTEP_A
#undef ACC

  float* dmb = DM + ((int64_t)(c * 32 + b)) * 36864;
#pragma unroll
  for (int m = 0; m < 9; m++)
#pragma unroll
    for (int ii = 0; ii < 4; ii++)
      dmb[m * 4096 + (ib + ii) * 64 + j] = D[m][ii];
}

// ---------------- phase B: in-place exclusive prefix (+M0) over chunks ----------------
__global__ void prefix_kernel(const float* __restrict__ M0, float* __restrict__ DM, int nc)
{
  int64_t e = (int64_t)blockIdx.x * blockDim.x + threadIdx.x;   // < 32*36864
  int b = (int)(e / 36864);
  int r = (int)(e % 36864);
  float run = M0[e];
  for (int cc = 0; cc < nc; cc++) {
    int64_t idx = ((int64_t)(cc * 32 + b)) * 36864 + r;
    float tmp = DM[idx];
    DM[idx] = run;
    run += tmp;
  }
}

// ---------------- phase C: intra-chunk recurrence + readout ----------------
__global__ __launch_bounds__(256) void chunk_scan_kernel(
    const float* __restrict__ Y, const float4* __restrict__ gate,
    const float* __restrict__ DM,   // holds Mstart(c) after prefix
    float* __restrict__ out, int ncMask, int ncShift, int L)
{
  __shared__ float sY[2 * TILEF];
  const int blk  = blockIdx.x;
  const int c    = blk & ncMask;
  const int rest = blk >> ncShift;
  const int jblk = rest & 3;
  const int b    = rest >> 2;
  const int tid  = threadIdx.x;
  const int lane = tid & 63;
  const int wv   = tid >> 6;        // 0..3
  const int igrp = lane & 15;
  const int jloc = lane >> 4;
  const int j    = jblk * 16 + wv * 4 + jloc;
  const int ib   = igrp * 4;
  const int srow_ = tid >> 5;
  const int rtid_ = tid & 31;
  const int t0   = c * L;
  const int NT   = L / 8;

  float M[9][4];
  const float* msb = DM + ((int64_t)(c * 32 + b)) * 36864;
#pragma unroll
  for (int m = 0; m < 9; m++)
#pragma unroll
    for (int ii = 0; ii < 4; ii++)
      M[m][ii] = msb[m * 4096 + (ib + ii) * 64 + j];

#define DO_SLOT(mm, gw, KK, VV) {                                            \
      M[mm][0] += KK.x * VV; M[mm][1] += KK.y * VV;                          \
      M[mm][2] += KK.z * VV; M[mm][3] += KK.w * VV;                          \
      Mc0 += (gw) * M[mm][0]; Mc1 += (gw) * M[mm][1];                        \
      Mc2 += (gw) * M[mm][2]; Mc3 += (gw) * M[mm][3]; }

    // routed slot == 0: add the delta unweighted too (all scatter-adds precede readout)
#define DO_SLOT0(gw, KK, VV) {                                               \
      float d0 = KK.x * VV, d1 = KK.y * VV, d2 = KK.z * VV, d3 = KK.w * VV;  \
      M[0][0] += d0; M[0][1] += d1; M[0][2] += d2; M[0][3] += d3;            \
      Mc0 += d0 + (gw) * M[0][0]; Mc1 += d1 + (gw) * M[0][1];                \
      Mc2 += d2 + (gw) * M[0][2]; Mc3 += d3 + (gw) * M[0][3]; }

#define CSTEP_C(P, R, TT) {                                                  \
    const float* rb = sY + (P) * TILEF + (R) * TROW;                         \
    float4 gl = *(const float4*)(rb + 448);                                  \
    float4 k0 = *(const float4*)(rb + ib);                                   \
    float4 ka = *(const float4*)(rb + 64 + ib);                              \
    float4 kb = *(const float4*)(rb + 128 + ib);                             \
    float v0 = rb[192 + j];                                                  \
    float va = rb[256 + j];                                                  \
    float vb = rb[320 + j];                                                  \
    float4 qv = *(const float4*)(rb + 384 + ib);                             \
    const int i0 = __float_as_int(gl.x);                                     \
    const int i1 = __float_as_int(gl.y);                                     \
    const float g0w = gl.z, g1w = gl.w;                                      \
    float Mc0, Mc1, Mc2, Mc3;                                                \
    M[0][0] += k0.x * v0; M[0][1] += k0.y * v0;                              \
    M[0][2] += k0.z * v0; M[0][3] += k0.w * v0;                              \
    Mc0 = M[0][0]; Mc1 = M[0][1]; Mc2 = M[0][2]; Mc3 = M[0][3];              \
    switch (i0) {                                                            \
      case 0: DO_SLOT0(g0w, ka, va); break;                                  \
      case 1: DO_SLOT(1, g0w, ka, va); break;                                \
      case 2: DO_SLOT(2, g0w, ka, va); break;                                \
      case 3: DO_SLOT(3, g0w, ka, va); break;                                \
      case 4: DO_SLOT(4, g0w, ka, va); break;                                \
      case 5: DO_SLOT(5, g0w, ka, va); break;                                \
      case 6: DO_SLOT(6, g0w, ka, va); break;                                \
      default: DO_SLOT(7, g0w, ka, va); break;                               \
    }                                                                        \
    switch (i1) {                                                            \
      case 0: DO_SLOT0(g1w, kb, vb); break;                                  \
      case 1: DO_SLOT(1, g1w, kb, vb); break;                                \
      case 2: DO_SLOT(2, g1w, kb, vb); break;                                \
      case 3: DO_SLOT(3, g1w, kb, vb); break;                                \
      case 4: DO_SLOT(4, g1w, kb, vb); break;                                \
      case 5: DO_SLOT(5, g1w, kb, vb); break;                                \
      case 6: DO_SLOT(6, g1w, kb, vb); break;                                \
      default: DO_SLOT(7, g1w, kb, vb); break;                               \
    }                                                                        \
    float part = qv.x * Mc0 + qv.y * Mc1 + qv.z * Mc2 + qv.w * Mc3;          \
    part = row16_sum(part);                                                  \
    if (igrp == 15)                                                          \
      out[(int64_t)(TT) * (BATCH * HID) + b * HID + j] = part; }

  STAGE_TILE(t0, 0);

  for (int tile = 0; tile < NT; ++tile) {
    const int p = tile & 1;
    __syncthreads();
#pragma unroll
    for (int r = 0; r < 8; r++) CSTEP_C(p, r, t0 + tile * 8 + r);
    if (tile + 1 < NT) STAGE_TILE(t0 + (tile + 1) * 8, p ^ 1);
  }
#undef CSTEP_C
#undef DO_SLOT
#undef DO_SLOT0

  if (c == ncMask) {   // last chunk owns M_final
    float* Mf = out + (int64_t)SEQ * BATCH * HID + (int64_t)b * 36864;
#pragma unroll
    for (int m = 0; m < 9; m++)
#pragma unroll
      for (int ii = 0; ii < 4; ii++)
        Mf[m * 4096 + (ib + ii) * 64 + j] = M[m][ii];
  }
}

// ---------------- launch ----------------
extern "C" void kernel_launch(void* const* d_in, const int* in_sizes, int n_in,
                              void* d_out, int out_size, void* d_ws, size_t ws_size,
                              hipStream_t stream)
{
  const float* X  = (const float*)d_in[0];
  const float* M0 = (const float*)d_in[1];
  const float* Wk = (const float*)d_in[2];
  const float* bk = (const float*)d_in[3];
  const float* Wv = (const float*)d_in[4];
  const float* bv = (const float*)d_in[5];
  const float* Wg = (const float*)d_in[6];
  const float* bg = (const float*)d_in[7];
  const float* Wq = (const float*)d_in[8];
  const float* bq = (const float*)d_in[9];

  char* ws = (char*)d_ws;
  short*  Xbf  = (short*)(ws + XBF_OFF);
  short*  Wbf  = (short*)(ws + WBF_OFF);
  float*  bb   = (float*)(ws + BB_OFF);
  float4* gate = (float4*)(ws + GATE_OFF);
  float*  Y    = (float*)(ws + Y_OFF);
  float*  out  = (float*)d_out;

  // chunk count: 8 if ws has room for a fresh ΔM region; else 4 chunks reusing
  // the Xbf/Wbf region (dead after gemm). ws_size is constant per deployment,
  // so this branch is deterministic across calls (graph-safe).
  int nc, ncShift; size_t dm_off;
  if (ws_size >= (size_t)DM8_END) { nc = 8; ncShift = 3; dm_off = DM8_OFF; }
  else                            { nc = 4; ncShift = 2; dm_off = 0; }
  const int L = SEQ / nc;
  float* DM = (float*)(ws + dm_off);

  prep_kernel<<<2048, 256, 0, stream>>>(X, Wk, bk, Wv, bv, Wg, bg, Wq, bq, Xbf, Wbf, bb);
  gate_kernel<<<ROWS / 4, 256, 0, stream>>>(X, Wg, bg, gate);
  dim3 gg(NPAD / 128, ROWS / 128);
  gemm_kernel<<<gg, 256, 0, stream>>>(Xbf, Wbf, bb, Y);
  chunk_accum_kernel<<<32 * nc * 4, 256, 0, stream>>>(Y, gate, DM, nc - 1, ncShift, L);
  prefix_kernel<<<(32 * 36864) / 256, 256, 0, stream>>>(M0, DM, nc);
  chunk_scan_kernel<<<32 * nc * 4, 256, 0, stream>>>(Y, gate, DM, out, nc - 1, ncShift, L);
}

// Round 10
// 267.224 us; speedup vs baseline: 1.1426x; 1.0033x over previous
//
#include <hip/hip_runtime.h>
#include <stdint.h>

#define SEQ 256
#define BATCH 32
#define IN_DIM 1024
#define HID 64
#define NPAD 1280
#define ROWS (SEQ*BATCH)   // 8192

// workspace byte offsets (all 256B aligned)
#define XBF_OFF   0
#define WBF_OFF   16777216
#define BB_OFF    19398656
#define GATE_OFF  19403776
#define Y_OFF     19534848
#define DM8_OFF   61477888   // 8-chunk ΔM (37,748,736 B) -> needs ws >= 99,226,624
#define DM8_END   99226624
// 4-chunk fallback ΔM (18,874,368 B) overlays Xbf/Wbf (dead after gemm)

// packed per-row record (written IN PLACE into the first 452 floats of each Y row):
// [k0(64) | ka(64) | kb(64) | v0(64) | va(64) | vb(64) | q(64) | gate(4)]
#define TROW 452
#define TILEF (8*TROW)   // 3616 floats per buffer; x2 buffers = 28,928 B LDS

typedef __attribute__((ext_vector_type(8))) short short8;
typedef __attribute__((ext_vector_type(4))) float floatx4;

// async global->LDS DMA, 16B per lane, dest = wave-uniform base + lane*16
typedef const __attribute__((address_space(1))) unsigned int gas_u32;
typedef __attribute__((address_space(3))) unsigned int las_u32;
static __device__ __forceinline__ void gl_lds16(const void* g, void* l) {
  __builtin_amdgcn_global_load_lds((gas_u32*)g, (las_u32*)l, 16, 0, 0);
}

static __device__ __forceinline__ short f2bf(float f) {
  union { float f; uint32_t u; } a; a.f = f;
  uint32_t r = (a.u + 0x7FFFu + ((a.u >> 16) & 1u)) >> 16;  // RNE
  return (short)r;
}

// ---------------- prep: fp32 -> bf16 for X, concat+convert weights, concat bias ----------------
__global__ void prep_kernel(const float* __restrict__ X,
                            const float* __restrict__ Wk, const float* __restrict__ bk,
                            const float* __restrict__ Wv, const float* __restrict__ bv,
                            const float* __restrict__ Wg, const float* __restrict__ bg,
                            const float* __restrict__ Wq, const float* __restrict__ bq,
                            short* __restrict__ Xbf, short* __restrict__ Wbf,
                            float* __restrict__ bb)
{
  int64_t idx = (int64_t)blockIdx.x * blockDim.x + threadIdx.x;
  int64_t stride = (int64_t)gridDim.x * blockDim.x;
  const int64_t NX4 = (int64_t)ROWS * IN_DIM / 4;
  for (int64_t i = idx; i < NX4; i += stride) {
    float4 x = ((const float4*)X)[i];
    short4 s4;
    s4.x = f2bf(x.x); s4.y = f2bf(x.y); s4.z = f2bf(x.z); s4.w = f2bf(x.w);
    ((short4*)Xbf)[i] = s4;
  }
  const int64_t NW4 = (int64_t)NPAD * IN_DIM / 4;
  for (int64_t i = idx; i < NW4; i += stride) {
    int64_t e = i * 4;
    int r = (int)(e >> 10);
    int k = (int)(e & 1023);
    float4 x;
    if (r < 576)       x = *(const float4*)(Wk + (int64_t)r*1024 + k);
    else if (r < 1152) x = *(const float4*)(Wv + (int64_t)(r-576)*1024 + k);
    else if (r < 1216) x = *(const float4*)(Wq + (int64_t)(r-1152)*1024 + k);
    else               x = make_float4(0.f, 0.f, 0.f, 0.f);   // gate cols unused (fp32 gate kernel)
    short4 s4;
    s4.x = f2bf(x.x); s4.y = f2bf(x.y); s4.z = f2bf(x.z); s4.w = f2bf(x.w);
    ((short4*)Wbf)[i] = s4;
  }
  for (int64_t i = idx; i < NPAD; i += stride) {
    int r = (int)i; float v;
    if (r < 576)       v = bk[r];
    else if (r < 1152) v = bv[r - 576];
    else if (r < 1216) v = bq[r - 1152];
    else               v = 0.f;
    bb[r] = v;
  }
}

// ---------------- GEMM: Y[8192,1280] = Xbf @ Wbf^T + bb ----------------
// 128x128 tile, BK=32, 256 thr, 2x2 wave grid, 4x4 MFMAs/wave, global_load_lds.
__global__ __launch_bounds__(256) void gemm_kernel(
    const short* __restrict__ Xbf,
    const short* __restrict__ Wbf,
    const float* __restrict__ bb,
    float* __restrict__ Y)
{
  __shared__ short As[128 * 32];   // 8 KB
  __shared__ short Bs[128 * 32];   // 8 KB

  const int tid  = threadIdx.x;
  const int lane = tid & 63;
  const int wv   = tid >> 6;     // 0..3
  const int quad = lane >> 4;    // 0..3
  const int cl   = lane & 15;
  const int wm   = wv & 1;       // wave M-half
  const int wn   = wv >> 1;      // wave N-half
  const int m0 = blockIdx.y * 128;
  const int n0 = blockIdx.x * 128;

  const int srow = wv * 32 + (lane >> 2);
  const int scol = (lane & 3) * 8;
  const short* gA = Xbf + (int64_t)(m0 + srow) * IN_DIM + scol;
  const short* gB = Wbf + (int64_t)(n0 + srow) * IN_DIM + scol;
  short* lA = As + (wv * 32) * 32;   // wave-uniform LDS base
  short* lB = Bs + (wv * 32) * 32;

  floatx4 acc[4][4];
#pragma unroll
  for (int i = 0; i < 4; i++)
#pragma unroll
    for (int k = 0; k < 4; k++) acc[i][k] = (floatx4){0.f, 0.f, 0.f, 0.f};

  for (int ks = 0; ks < IN_DIM; ks += 32) {
    gl_lds16(gA + ks,                lA);
    gl_lds16(gA + 16 * IN_DIM + ks,  lA + 16 * 32);
    gl_lds16(gB + ks,                lB);
    gl_lds16(gB + 16 * IN_DIM + ks,  lB + 16 * 32);
    __syncthreads();   // drains vmcnt (DMA) before barrier

    short8 bfrag[4], afrag[4];
#pragma unroll
    for (int nt = 0; nt < 4; nt++)
      bfrag[nt] = *(const short8*)(&Bs[(wn * 64 + nt * 16 + cl) * 32 + quad * 8]);
#pragma unroll
    for (int mt = 0; mt < 4; mt++)
      afrag[mt] = *(const short8*)(&As[(wm * 64 + mt * 16 + cl) * 32 + quad * 8]);
#pragma unroll
    for (int mt = 0; mt < 4; mt++)
#pragma unroll
      for (int nt = 0; nt < 4; nt++)
        acc[mt][nt] = __builtin_amdgcn_mfma_f32_16x16x32_bf16(afrag[mt], bfrag[nt], acc[mt][nt], 0, 0, 0);
    __syncthreads();
  }

#pragma unroll
  for (int nt = 0; nt < 4; nt++) {
    const int col = n0 + wn * 64 + nt * 16 + cl;
    const float bias = bb[col];
#pragma unroll
    for (int mt = 0; mt < 4; mt++) {
#pragma unroll
      for (int r = 0; r < 4; r++) {
        int row = m0 + wm * 64 + mt * 16 + quad * 4 + r;
        Y[(int64_t)row * NPAD + col] = acc[mt][nt][r] + bias;
      }
    }
  }
}

// ---------------- gate (fp32-exact): logits from X,Wg; top-2 + renormalized weights ----------------
__global__ __launch_bounds__(256) void gate_kernel(
    const float* __restrict__ X,
    const float* __restrict__ Wg, const float* __restrict__ bg,
    float4* __restrict__ gate)
{
  const int lane = threadIdx.x & 63;
  const int row  = blockIdx.x * 4 + (threadIdx.x >> 6);
  const float* x = X + (int64_t)row * IN_DIM;

  float acc[8];
#pragma unroll
  for (int e = 0; e < 8; e++) acc[e] = 0.f;

#pragma unroll
  for (int i = 0; i < 4; i++) {
    const int off = i * 256 + lane * 4;
    float4 xv = *(const float4*)(x + off);
#pragma unroll
    for (int e = 0; e < 8; e++) {
      float4 wv = *(const float4*)(Wg + e * IN_DIM + off);
      acc[e] += xv.x * wv.x + xv.y * wv.y + xv.z * wv.z + xv.w * wv.w;
    }
  }
#pragma unroll
  for (int e = 0; e < 8; e++) {
#pragma unroll
    for (int m = 32; m >= 1; m >>= 1)
      acc[e] += __shfl_xor(acc[e], m);
    acc[e] += bg[e];
  }

  if (lane == 0) {
    int i0 = 0; float v0 = acc[0];
#pragma unroll
    for (int e = 1; e < 8; e++) if (acc[e] > v0) { v0 = acc[e]; i0 = e; }
    int i1 = -1; float v1 = -3.4e38f;
#pragma unroll
    for (int e = 0; e < 8; e++) if (e != i0 && acc[e] > v1) { v1 = acc[e]; i1 = e; }
    float e1 = __expf(v1 - v0);
    float inv = 1.f / (1.f + e1);
    gate[row] = make_float4(__int_as_float(i0), __int_as_float(i1), inv, e1 * inv);
  }
}

// ---------------- pack: gather gate-routed segments, rewrite row IN PLACE ----------------
// R9 post-mortem: both chunk kernels were bound by ~450 GB/s effective scattered
// gather (dur ≈ hbm_bytes/450GB/s in R7 AND R9, two different structures). Pay
// the gather ONCE here: one wave per row, 8192 independent waves = thousands of
// loads in flight (latency-immune). Record [k0|ka|kb|v0|va|vb|q|gate] lands at
// Yrow[0..452). In-place safe: loads precede stores (same-pointer aliasing pins
// the order), waves own disjoint rows.
__global__ __launch_bounds__(256) void pack_kernel(
    float* __restrict__ Y, const float4* __restrict__ gate)
{
  const int row  = blockIdx.x * 4 + (threadIdx.x >> 6);   // r = t*BATCH+b
  const int lane = threadIdx.x & 63;
  float* Yp = Y + (int64_t)row * NPAD;
  float4 g = gate[row];
  const int i0 = __float_as_int(g.x), i1 = __float_as_int(g.y);

  // idx -> source address per record layout
#define PSRC(IDX) ({                                                 \
    const int seg = (IDX) >> 4;                                      \
    const int off = ((IDX) & 15) * 4;                                \
    const int base = (seg == 6) ? 1152 : ((seg >= 3) ? 576 : 0);     \
    const int s3 = (seg >= 3 && seg < 6) ? seg - 3 : seg;            \
    const int slot = (s3 == 1) ? i0 * 64 : ((s3 == 2) ? i1 * 64 : 0);\
    (const float4*)(Yp + base + slot + off); })

  float4 r0 = *PSRC(lane);                       // idx 0..63 (k0,ka,kb,v0)
  float4 r1;
  if (lane < 48) r1 = *PSRC(64 + lane);          // idx 64..111 (va,vb,q)
  // all loads above complete before any store below (same-pointer ordering)
  *(float4*)(Yp + lane * 4) = r0;
  if (lane < 48) *(float4*)(Yp + (64 + lane) * 4) = r1;
  if (lane == 48) *(float4*)(Yp + 448) = g;      // idx 112 = gate
#undef PSRC
}

// 16-lane (DPP row) sum; result valid in lane (lane&15)==15 of each row.
static __device__ __forceinline__ float row16_sum(float x) {
  float r = x;
  r += __int_as_float(__builtin_amdgcn_update_dpp(0, __float_as_int(r), 0x118, 0xf, 0xf, false)); // row_shr:8
  r += __int_as_float(__builtin_amdgcn_update_dpp(0, __float_as_int(r), 0x114, 0xf, 0xf, false)); // row_shr:4
  r += __int_as_float(__builtin_amdgcn_update_dpp(0, __float_as_int(r), 0x112, 0xf, 0xf, false)); // row_shr:2
  r += __int_as_float(__builtin_amdgcn_update_dpp(0, __float_as_int(r), 0x111, 0xf, 0xf, false)); // row_shr:1
  return r;
}

// ======================= chunked scan, LDS tiles staged from packed rows =======================
// Staging is now a LINEAR contiguous copy (113 float4/row, static addresses, no
// gate dependency) — sequential L2-prefetch-friendly streams. Order per tile:
// sync -> compute(p) -> stage(p^1), stage = load->immediate ds_write (no spill).

#define STAGE_TILE(TBASE, DST) {                                     \
    const int trow = (TBASE) + srow_;                                \
    const float* Yp = Y + ((int64_t)trow * BATCH + b) * NPAD;        \
    float* dbuf = sY + (DST) * TILEF + srow_ * TROW;                 \
    _Pragma("unroll")                                                \
    for (int k = 0; k < 4; k++) {                                    \
      const int idx = rtid_ + 32 * k;                                \
      if (idx < 113)                                                 \
        *(float4*)(dbuf + idx * 4) = *(const float4*)(Yp + idx * 4); \
    } }

// ---------------- phase A: per-chunk delta accumulation ----------------
__global__ __launch_bounds__(256) void chunk_accum_kernel(
    const float* __restrict__ Y, const float4* __restrict__ gate,
    float* __restrict__ DM, int ncMask, int ncShift, int L)
{
  __shared__ float sY[2 * TILEF];
  const int blk  = blockIdx.x;
  const int c    = blk & ncMask;
  const int rest = blk >> ncShift;
  const int jblk = rest & 3;
  const int b    = rest >> 2;
  const int tid  = threadIdx.x;
  const int lane = tid & 63;
  const int wv   = tid >> 6;        // 0..3
  const int igrp = lane & 15;
  const int jloc = lane >> 4;
  const int j    = jblk * 16 + wv * 4 + jloc;
  const int ib   = igrp * 4;
  const int srow_ = tid >> 5;       // 0..7 (staging row)
  const int rtid_ = tid & 31;
  const int t0   = c * L;
  const int NT   = L / 8;

  float D[9][4];
#pragma unroll
  for (int m = 0; m < 9; m++)
#pragma unroll
    for (int ii = 0; ii < 4; ii++) D[m][ii] = 0.f;

#define ACC(mm, KK, VV) {                                   \
    D[mm][0] += KK.x * VV; D[mm][1] += KK.y * VV;           \
    D[mm][2] += KK.z * VV; D[mm][3] += KK.w * VV; }

#define CSTEP_A(P, R) {                                     \
    const float* rb = sY + (P) * TILEF + (R) * TROW;        \
    float4 gl = *(const float4*)(rb + 448);                 \
    float4 k0 = *(const float4*)(rb + ib);                  \
    float4 ka = *(const float4*)(rb + 64 + ib);             \
    float4 kb = *(const float4*)(rb + 128 + ib);            \
    float v0 = rb[192 + j];                                 \
    float va = rb[256 + j];                                 \
    float vb = rb[320 + j];                                 \
    const int i0 = __float_as_int(gl.x);                    \
    const int i1 = __float_as_int(gl.y);                    \
    ACC(0, k0, v0);                                         \
    switch (i0) {                                           \
      case 0: ACC(0, ka, va); break;                        \
      case 1: ACC(1, ka, va); break;                        \
      case 2: ACC(2, ka, va); break;                        \
      case 3: ACC(3, ka, va); break;                        \
      case 4: ACC(4, ka, va); break;                        \
      case 5: ACC(5, ka, va); break;                        \
      case 6: ACC(6, ka, va); break;                        \
      default: ACC(7, ka, va); break;                       \
    }                                                       \
    switch (i1) {                                           \
      case 0: ACC(0, kb, vb); break;                        \
      case 1: ACC(1, kb, vb); break;                        \
      case 2: ACC(2, kb, vb); break;                        \
      case 3: ACC(3, kb, vb); break;                        \
      case 4: ACC(4, kb, vb); break;                        \
      case 5: ACC(5, kb, vb); break;                        \
      case 6: ACC(6, kb, vb); break;                        \
      default: ACC(7, kb, vb); break;                       \
    } }

  STAGE_TILE(t0, 0);

  for (int tile = 0; tile < NT; ++tile) {
    const int p = tile & 1;
    __syncthreads();
#pragma unroll
    for (int r = 0; r < 8; r++) CSTEP_A(p, r);
    if (tile + 1 < NT) STAGE_TILE(t0 + (tile + 1) * 8, p ^ 1);
  }
#undef CSTEP_A
#undef ACC

  float* dmb = DM + ((int64_t)(c * 32 + b)) * 36864;
#pragma unroll
  for (int m = 0; m < 9; m++)
#pragma unroll
    for (int ii = 0; ii < 4; ii++)
      dmb[m * 4096 + (ib + ii) * 64 + j] = D[m][ii];
}

// ---------------- phase B: in-place exclusive prefix (+M0) over chunks ----------------
__global__ void prefix_kernel(const float* __restrict__ M0, float* __restrict__ DM, int nc)
{
  int64_t e = (int64_t)blockIdx.x * blockDim.x + threadIdx.x;   // < 32*36864
  int b = (int)(e / 36864);
  int r = (int)(e % 36864);
  float run = M0[e];
  for (int cc = 0; cc < nc; cc++) {
    int64_t idx = ((int64_t)(cc * 32 + b)) * 36864 + r;
    float tmp = DM[idx];
    DM[idx] = run;
    run += tmp;
  }
}

// ---------------- phase C: intra-chunk recurrence + readout ----------------
__global__ __launch_bounds__(256) void chunk_scan_kernel(
    const float* __restrict__ Y, const float4* __restrict__ gate,
    const float* __restrict__ DM,   // holds Mstart(c) after prefix
    float* __restrict__ out, int ncMask, int ncShift, int L)
{
  __shared__ float sY[2 * TILEF];
  const int blk  = blockIdx.x;
  const int c    = blk & ncMask;
  const int rest = blk >> ncShift;
  const int jblk = rest & 3;
  const int b    = rest >> 2;
  const int tid  = threadIdx.x;
  const int lane = tid & 63;
  const int wv   = tid >> 6;        // 0..3
  const int igrp = lane & 15;
  const int jloc = lane >> 4;
  const int j    = jblk * 16 + wv * 4 + jloc;
  const int ib   = igrp * 4;
  const int srow_ = tid >> 5;
  const int rtid_ = tid & 31;
  const int t0   = c * L;
  const int NT   = L / 8;

  float M[9][4];
  const float* msb = DM + ((int64_t)(c * 32 + b)) * 36864;
#pragma unroll
  for (int m = 0; m < 9; m++)
#pragma unroll
    for (int ii = 0; ii < 4; ii++)
      M[m][ii] = msb[m * 4096 + (ib + ii) * 64 + j];

#define DO_SLOT(mm, gw, KK, VV) {                                            \
      M[mm][0] += KK.x * VV; M[mm][1] += KK.y * VV;                          \
      M[mm][2] += KK.z * VV; M[mm][3] += KK.w * VV;                          \
      Mc0 += (gw) * M[mm][0]; Mc1 += (gw) * M[mm][1];                        \
      Mc2 += (gw) * M[mm][2]; Mc3 += (gw) * M[mm][3]; }

    // routed slot == 0: add the delta unweighted too (all scatter-adds precede readout)
#define DO_SLOT0(gw, KK, VV) {                                               \
      float d0 = KK.x * VV, d1 = KK.y * VV, d2 = KK.z * VV, d3 = KK.w * VV;  \
      M[0][0] += d0; M[0][1] += d1; M[0][2] += d2; M[0][3] += d3;            \
      Mc0 += d0 + (gw) * M[0][0]; Mc1 += d1 + (gw) * M[0][1];                \
      Mc2 += d2 + (gw) * M[0][2]; Mc3 += d3 + (gw) * M[0][3]; }

#define CSTEP_C(P, R, TT) {                                                  \
    const float* rb = sY + (P) * TILEF + (R) * TROW;                         \
    float4 gl = *(const float4*)(rb + 448);                                  \
    float4 k0 = *(const float4*)(rb + ib);                                   \
    float4 ka = *(const float4*)(rb + 64 + ib);                              \
    float4 kb = *(const float4*)(rb + 128 + ib);                             \
    float v0 = rb[192 + j];                                                  \
    float va = rb[256 + j];                                                  \
    float vb = rb[320 + j];                                                  \
    float4 qv = *(const float4*)(rb + 384 + ib);                             \
    const int i0 = __float_as_int(gl.x);                                     \
    const int i1 = __float_as_int(gl.y);                                     \
    const float g0w = gl.z, g1w = gl.w;                                      \
    float Mc0, Mc1, Mc2, Mc3;                                                \
    M[0][0] += k0.x * v0; M[0][1] += k0.y * v0;                              \
    M[0][2] += k0.z * v0; M[0][3] += k0.w * v0;                              \
    Mc0 = M[0][0]; Mc1 = M[0][1]; Mc2 = M[0][2]; Mc3 = M[0][3];              \
    switch (i0) {                                                            \
      case 0: DO_SLOT0(g0w, ka, va); break;                                  \
      case 1: DO_SLOT(1, g0w, ka, va); break;                                \
      case 2: DO_SLOT(2, g0w, ka, va); break;                                \
      case 3: DO_SLOT(3, g0w, ka, va); break;                                \
      case 4: DO_SLOT(4, g0w, ka, va); break;                                \
      case 5: DO_SLOT(5, g0w, ka, va); break;                                \
      case 6: DO_SLOT(6, g0w, ka, va); break;                                \
      default: DO_SLOT(7, g0w, ka, va); break;                               \
    }                                                                        \
    switch (i1) {                                                            \
      case 0: DO_SLOT0(g1w, kb, vb); break;                                  \
      case 1: DO_SLOT(1, g1w, kb, vb); break;                                \
      case 2: DO_SLOT(2, g1w, kb, vb); break;                                \
      case 3: DO_SLOT(3, g1w, kb, vb); break;                                \
      case 4: DO_SLOT(4, g1w, kb, vb); break;                                \
      case 5: DO_SLOT(5, g1w, kb, vb); break;                                \
      case 6: DO_SLOT(6, g1w, kb, vb); break;                                \
      default: DO_SLOT(7, g1w, kb, vb); break;                               \
    }                                                                        \
    float part = qv.x * Mc0 + qv.y * Mc1 + qv.z * Mc2 + qv.w * Mc3;          \
    part = row16_sum(part);                                                  \
    if (igrp == 15)                                                          \
      out[(int64_t)(TT) * (BATCH * HID) + b * HID + j] = part; }

  STAGE_TILE(t0, 0);

  for (int tile = 0; tile < NT; ++tile) {
    const int p = tile & 1;
    __syncthreads();
#pragma unroll
    for (int r = 0; r < 8; r++) CSTEP_C(p, r, t0 + tile * 8 + r);
    if (tile + 1 < NT) STAGE_TILE(t0 + (tile + 1) * 8, p ^ 1);
  }
#undef CSTEP_C
#undef DO_SLOT
#undef DO_SLOT0

  if (c == ncMask) {   // last chunk owns M_final
    float* Mf = out + (int64_t)SEQ * BATCH * HID + (int64_t)b * 36864;
#pragma unroll
    for (int m = 0; m < 9; m++)
#pragma unroll
      for (int ii = 0; ii < 4; ii++)
        Mf[m * 4096 + (ib + ii) * 64 + j] = M[m][ii];
  }
}

// ---------------- launch ----------------
extern "C" void kernel_launch(void* const* d_in, const int* in_sizes, int n_in,
                              void* d_out, int out_size, void* d_ws, size_t ws_size,
                              hipStream_t stream)
{
  const float* X  = (const float*)d_in[0];
  const float* M0 = (const float*)d_in[1];
  const float* Wk = (const float*)d_in[2];
  const float* bk = (const float*)d_in[3];
  const float* Wv = (const float*)d_in[4];
  const float* bv = (const float*)d_in[5];
  const float* Wg = (const float*)d_in[6];
  const float* bg = (const float*)d_in[7];
  const float* Wq = (const float*)d_in[8];
  const float* bq = (const float*)d_in[9];

  char* ws = (char*)d_ws;
  short*  Xbf  = (short*)(ws + XBF_OFF);
  short*  Wbf  = (short*)(ws + WBF_OFF);
  float*  bb   = (float*)(ws + BB_OFF);
  float4* gate = (float4*)(ws + GATE_OFF);
  float*  Y    = (float*)(ws + Y_OFF);
  float*  out  = (float*)d_out;

  // chunk count: 8 if ws has room for a fresh ΔM region; else 4 chunks reusing
  // the Xbf/Wbf region (dead after gemm). ws_size is constant per deployment,
  // so this branch is deterministic across calls (graph-safe).
  int nc, ncShift; size_t dm_off;
  if (ws_size >= (size_t)DM8_END) { nc = 8; ncShift = 3; dm_off = DM8_OFF; }
  else                            { nc = 4; ncShift = 2; dm_off = 0; }
  const int L = SEQ / nc;
  float* DM = (float*)(ws + dm_off);

  prep_kernel<<<2048, 256, 0, stream>>>(X, Wk, bk, Wv, bv, Wg, bg, Wq, bq, Xbf, Wbf, bb);
  gate_kernel<<<ROWS / 4, 256, 0, stream>>>(X, Wg, bg, gate);
  dim3 gg(NPAD / 128, ROWS / 128);
  gemm_kernel<<<gg, 256, 0, stream>>>(Xbf, Wbf, bb, Y);
  pack_kernel<<<ROWS / 4, 256, 0, stream>>>(Y, gate);
  chunk_accum_kernel<<<32 * nc * 4, 256, 0, stream>>>(Y, gate, DM, nc - 1, ncShift, L);
  prefix_kernel<<<(32 * 36864) / 256, 256, 0, stream>>>(M0, DM, nc);
  chunk_scan_kernel<<<32 * nc * 4, 256, 0, stream>>>(Y, gate, DM, out, nc - 1, ncShift, L);
}